// Round 2
// baseline (5671.815 us; speedup 1.0000x reference)
//
#include <hip/hip_runtime.h>
#include <cmath>

#define B_  16
#define C_  256
#define H_  1024
#define S_  1024
#define E_  512
#define NH_ 8
#define DD_ 512
#define DS_ 64
#define HD_ 64
#define S1_ 1025
#define RELM 2048

#define BK 16
#define BM 64
#define BN 64
#define PAD 68   // padded LDS row (68 floats): float4-aligned, 2-way banks only (free on gfx950)

__device__ __forceinline__ unsigned short f2bf(float f) {
    unsigned u = __float_as_uint(f);
    u += 0x7fffu + ((u >> 16) & 1u);   // RNE
    return (unsigned short)(u >> 16);
}
__device__ __forceinline__ float bf2f(unsigned short h) {
    return __uint_as_float((unsigned)h << 16);
}

// C[m,n] = sum_k A[m,k] * W[n,k] + bias[n]
// !ATRANS: A row-major (M,K). ATRANS: A[m,k] at (m/rpb_in)*(K*rpb_in) + k*rpb_in + (m%rpb_in)
// out row remap: orow = (m/rpb_in)*rpb_out + m%rpb_in.  OutT: float or unsigned short (bf16)
template<bool ATRANS, typename OutT>
__global__ __launch_bounds__(256)
void gemm_wt(const float* __restrict__ A, const float* __restrict__ W,
             const float* __restrict__ bias, OutT* __restrict__ Cmat,
             int M, int N, int K, int rpb_in, int rpb_out)
{
    __shared__ float As[BK][PAD];
    __shared__ float Ws[BK][PAD];
    const int tx = threadIdx.x, ty = threadIdx.y;
    const int tid = ty * 16 + tx;
    const int m0 = blockIdx.y * BM;
    const int n0 = blockIdx.x * BN;
    float acc[4][4] = {};
    for (int k0 = 0; k0 < K; k0 += BK) {
        if constexpr (!ATRANS) {
            int c = tid & 15, r = tid >> 4;
#pragma unroll
            for (int i = 0; i < 4; i++) {
                int m = m0 + r + i * 16;
                As[c][r + i * 16] = (m < M) ? A[(size_t)m * K + k0 + c] : 0.f;
            }
        } else {
            // tile rows stay within one batch (rpb_in % 64 == 0, M % 64 == 0)
            int h = tid & 63, kt = tid >> 6;
            int bb = m0 / rpb_in;
            int hbase = m0 % rpb_in;
            const float* Ab = A + (size_t)bb * K * rpb_in + hbase + h;
#pragma unroll
            for (int i = 0; i < 4; i++) {
                int k = k0 + kt + i * 4;
                As[kt + i * 4][h] = Ab[(size_t)k * rpb_in];
            }
        }
        {
            int c = tid & 15, r = tid >> 4;
#pragma unroll
            for (int i = 0; i < 4; i++) {
                int n = n0 + r + i * 16;
                Ws[c][r + i * 16] = W[(size_t)n * K + k0 + c];
            }
        }
        __syncthreads();
#pragma unroll
        for (int kk = 0; kk < BK; kk++) {
            float4 a4 = *(const float4*)&As[kk][ty * 4];
            float4 w4 = *(const float4*)&Ws[kk][tx * 4];
            float av[4] = {a4.x, a4.y, a4.z, a4.w};
            float wv[4] = {w4.x, w4.y, w4.z, w4.w};
#pragma unroll
            for (int i = 0; i < 4; i++)
#pragma unroll
                for (int j = 0; j < 4; j++)
                    acc[i][j] += av[i] * wv[j];
        }
        __syncthreads();
    }
#pragma unroll
    for (int i = 0; i < 4; i++) {
        int m = m0 + ty * 4 + i;
        if (m < M) {
            int orow = (m / rpb_in) * rpb_out + (m % rpb_in);
            const float* bp = bias + n0 + tx * 4;
            if constexpr (sizeof(OutT) == 2) {
                unsigned short* cp = (unsigned short*)Cmat + (size_t)orow * N + n0 + tx * 4;
                ushort4 pk;
                pk.x = f2bf(acc[i][0] + bp[0]);
                pk.y = f2bf(acc[i][1] + bp[1]);
                pk.z = f2bf(acc[i][2] + bp[2]);
                pk.w = f2bf(acc[i][3] + bp[3]);
                *(ushort4*)cp = pk;
            } else {
                float* cp = (float*)Cmat + (size_t)orow * N + n0 + tx * 4;
#pragma unroll
                for (int j = 0; j < 4; j++)
                    cp[j] = acc[i][j] + bp[j];
            }
        }
    }
}

// WqW[e,c] = sum_k ipW[e,k] * q_W[k,c];  qb2[e] = sum_k ipW[e,k]*q_b[k] + ipb[e]
__global__ __launch_bounds__(256)
void fuse_qw_kernel(const float* __restrict__ ipW, const float* __restrict__ ipb,
                    const float* __restrict__ q_W, const float* __restrict__ q_b,
                    float* __restrict__ WqW, float* __restrict__ qb2)
{
    const int e = blockIdx.x;       // [0, E)
    const int c = threadIdx.x;      // [0, C)
    const float* wrow = ipW + (size_t)e * E_;
    float acc = 0.f;
    for (int k = 0; k < E_; k++) acc += wrow[k] * q_W[(size_t)k * C_ + c];
    WqW[(size_t)e * C_ + c] = acc;
    __shared__ float red[256];
    float bacc = 0.f;
    for (int k = c; k < E_; k += 256) bacc += wrow[k] * q_b[k];
    red[c] = bacc;
    __syncthreads();
    for (int s = 128; s > 0; s >>= 1) {
        if (c < s) red[c] += red[c + s];
        __syncthreads();
    }
    if (c == 0) qb2[e] = red[0] + ipb[e];
}

// static token + FiLM MLP; writes static row into cond buffer; scale = 1 + tanh(film)
__global__ __launch_bounds__(256)
void static_film_kernel(const float* __restrict__ statIn,
                        const float* __restrict__ stat_W, const float* __restrict__ stat_b,
                        const float* __restrict__ fW1, const float* __restrict__ fb1,
                        const float* __restrict__ fW2, const float* __restrict__ fb2,
                        float* __restrict__ cond, float* __restrict__ scaleOut)
{
    __shared__ float s_sh[DS_];
    __shared__ float st_sh[E_];
    __shared__ float h1_sh[E_];
    const int b = blockIdx.x, t = threadIdx.x;
    if (t < DS_) s_sh[t] = statIn[b * DS_ + t];
    __syncthreads();
    for (int e = t; e < E_; e += 256) {
        float acc = stat_b[e];
#pragma unroll 4
        for (int j = 0; j < DS_; j++) acc += s_sh[j] * stat_W[e * DS_ + j];
        st_sh[e] = acc;
        cond[((size_t)(b * S1_ + S_)) * E_ + e] = acc;
    }
    __syncthreads();
    for (int e = t; e < E_; e += 256) {
        float acc = fb1[e];
#pragma unroll 4
        for (int j = 0; j < E_; j++) acc += st_sh[j] * fW1[(size_t)e * E_ + j];
        h1_sh[e] = (acc >= 0.f) ? acc : 0.1f * acc;
    }
    __syncthreads();
    for (int c = t; c < C_; c += 256) {
        float acc = fb2[c];
#pragma unroll 4
        for (int j = 0; j < E_; j++) acc += h1_sh[j] * fW2[(size_t)c * E_ + j];
        scaleOut[b * C_ + c] = 1.f + tanhf(acc);
    }
}

// one wave per (b, nh, qi); lane = head dim. Causal: only k<=qi plus static k=S.
// q/k/v stored as bf16 (raw ushort).
__global__ __launch_bounds__(256)
void attn_kernel(const unsigned short* __restrict__ q, const unsigned short* __restrict__ k,
                 const unsigned short* __restrict__ v, const float* __restrict__ bt,
                 float* __restrict__ ctx)
{
    const int wave = (blockIdx.x << 2) | (threadIdx.x >> 6);
    const int lane = threadIdx.x & 63;
    const int qi = wave & (H_ - 1);
    const int rem = wave >> 10;
    const int nh = rem & (NH_ - 1);
    const int b = rem >> 3;

    const unsigned short* qp = q + ((size_t)(b * H_ + qi)) * E_ + nh * HD_;
    const size_t kvbase = (size_t)b * S1_ * E_ + nh * HD_ + lane;
    const unsigned short* kp = k + kvbase;
    const unsigned short* vp = v + kvbase;
    const float qv = bf2f(qp[lane]) * 0.125f;     // 1/sqrt(64), exact pow2
    const float* btq = bt + qi + (RELM - 1);

    float l = 0.f, o = 0.f;
    for (int kk = 0; kk <= qi; kk++) {
        float s = qv * bf2f(kp[(size_t)kk * E_]);
#pragma unroll
        for (int off = 32; off > 0; off >>= 1) s += __shfl_xor(s, off, 64);
        float p = __expf(s + btq[-kk]);      // scores bounded ~|0.1|: no max-sub needed
        l += p;
        o += p * bf2f(vp[(size_t)kk * E_]);
    }
    {   // static token, always visible
        float s = qv * bf2f(kp[(size_t)S_ * E_]);
#pragma unroll
        for (int off = 32; off > 0; off >>= 1) s += __shfl_xor(s, off, 64);
        float p = __expf(s + btq[-S_]);
        l += p;
        o += p * bf2f(vp[(size_t)S_ * E_]);
    }
    ctx[((size_t)(b * H_ + qi)) * E_ + nh * HD_ + lane] = o / l;
}

// out[b,c,h] = (x[b,c,h] + sum_e ctxo[b,h,e]*ctx_W[c,e] + ctx_b[c]) * scale[b,c]
__global__ __launch_bounds__(256)
void final_kernel(const float* __restrict__ ctxo, const float* __restrict__ ctx_W,
                  const float* __restrict__ ctx_b, const float* __restrict__ x,
                  const float* __restrict__ scale, float* __restrict__ out)
{
    __shared__ float Asm[BK][PAD];
    __shared__ float Bsm[BK][PAD];
    const int tx = threadIdx.x, ty = threadIdx.y;
    const int tid = ty * 16 + tx;
    const int b = blockIdx.z;
    const int c0 = blockIdx.y * 64;
    const int h0 = blockIdx.x * 64;
    float acc[4][4] = {};
    for (int e0 = 0; e0 < E_; e0 += BK) {
        int ee = tid & 15, r = tid >> 4;
#pragma unroll
        for (int i = 0; i < 4; i++) {
            Asm[ee][r + i * 16] = ctx_W[(size_t)(c0 + r + i * 16) * E_ + e0 + ee];
            Bsm[ee][r + i * 16] = ctxo[((size_t)b * H_ + h0 + r + i * 16) * E_ + e0 + ee];
        }
        __syncthreads();
#pragma unroll
        for (int kk = 0; kk < BK; kk++) {
            float4 a4 = *(const float4*)&Asm[kk][ty * 4];
            float4 b4 = *(const float4*)&Bsm[kk][tx * 4];
            float av[4] = {a4.x, a4.y, a4.z, a4.w};
            float bv[4] = {b4.x, b4.y, b4.z, b4.w};
#pragma unroll
            for (int i = 0; i < 4; i++)
#pragma unroll
                for (int j = 0; j < 4; j++)
                    acc[i][j] += av[i] * bv[j];
        }
        __syncthreads();
    }
#pragma unroll
    for (int i = 0; i < 4; i++) {
        int c = c0 + ty * 4 + i;
        float sc = scale[b * C_ + c];
        float cb = ctx_b[c];
        const float* xp = x + ((size_t)b * C_ + c) * H_ + h0 + tx * 4;
        float* op = out + ((size_t)b * C_ + c) * H_ + h0 + tx * 4;
#pragma unroll
        for (int j = 0; j < 4; j++)
            op[j] = (xp[j] + acc[i][j] + cb) * sc;
    }
}

extern "C" void kernel_launch(void* const* d_in, const int* in_sizes, int n_in,
                              void* d_out, int out_size, void* d_ws, size_t ws_size,
                              hipStream_t stream)
{
    (void)in_sizes; (void)n_in; (void)out_size; (void)ws_size;
    const float* x      = (const float*)d_in[0];
    const float* dyn    = (const float*)d_in[1];
    const float* statIn = (const float*)d_in[2];
    const float* dyn_W  = (const float*)d_in[3];
    const float* dyn_b  = (const float*)d_in[4];
    const float* stat_W = (const float*)d_in[5];
    const float* stat_b = (const float*)d_in[6];
    const float* fW1    = (const float*)d_in[7];
    const float* fb1    = (const float*)d_in[8];
    const float* fW2    = (const float*)d_in[9];
    const float* fb2    = (const float*)d_in[10];
    const float* ipW    = (const float*)d_in[13];
    const float* ipb    = (const float*)d_in[14];
    const float* out_W  = (const float*)d_in[15];
    const float* out_b  = (const float*)d_in[16];
    const float* ctx_W  = (const float*)d_in[17];
    const float* ctx_b  = (const float*)d_in[18];
    const float* bt     = (const float*)d_in[19];
    const float* q_W    = (const float*)d_in[11];
    const float* q_b    = (const float*)d_in[12];
    float* out = (float*)d_out;

    // ---- workspace layout (total ~84.5 MB; fits well under harness ws) ----
    char* w = (char*)d_ws;
    size_t off = 0;
    float* cond   = (float*)(w + off); off += (size_t)B_ * S1_ * E_ * 4;   // 33,587,200
    float* scaleB = (float*)(w + off); off += (size_t)B_ * C_ * 4;         // 16,384
    float* WqW    = (float*)(w + off); off += (size_t)E_ * C_ * 4;         // 524,288
    float* qb2    = (float*)(w + off); off += E_ * 4;                      // 2,048
    unsigned short* q16 = (unsigned short*)(w + off);                      // B*H*E bf16
    unsigned short* k16 = q16 + (size_t)B_ * H_  * E_;                     // B*S1*E bf16
    unsigned short* v16 = k16 + (size_t)B_ * S1_ * E_;                     // B*S1*E bf16
    // aliases over dead regions:
    float* ctxB  = cond;           // cond dead after K/V projections
    float* ctxoB = (float*)q16;    // q16/k16 dead after attention (33.5MB <= 50.4MB)

    dim3 blk(16, 16);
    // 1. dyn_tokens -> cond rows [b*S1 + s]  (fp32)
    gemm_wt<false, float><<<dim3(E_ / 64, (B_ * S_) / 64), blk, 0, stream>>>(
        dyn, dyn_W, dyn_b, cond, B_ * S_, E_, DD_, S_, S1_);
    // 2. static token (into cond row b*S1+S) + FiLM scale
    static_film_kernel<<<B_, 256, 0, stream>>>(statIn, stat_W, stat_b, fW1, fb1, fW2, fb2,
                                               cond, scaleB);
    // 3. fused query weight: WqW = Wq @ q_W, qb2 = Wq @ q_b + bq
    fuse_qw_kernel<<<E_, C_, 0, stream>>>(ipW, ipb, q_W, q_b, WqW, qb2);
    // 4. q[b,h,e] = sum_c x[b,c,h]*WqW[e,c] + qb2[e]  -> bf16
    gemm_wt<true, unsigned short><<<dim3(E_ / 64, (B_ * H_) / 64), blk, 0, stream>>>(
        x, WqW, qb2, q16, B_ * H_, E_, C_, H_, H_);
    // 5. k / v projections -> bf16
    gemm_wt<false, unsigned short><<<dim3(E_ / 64, (B_ * S1_ + 63) / 64), blk, 0, stream>>>(
        cond, ipW + (size_t)E_ * E_, ipb + E_, k16, B_ * S1_, E_, E_, S1_, S1_);
    gemm_wt<false, unsigned short><<<dim3(E_ / 64, (B_ * S1_ + 63) / 64), blk, 0, stream>>>(
        cond, ipW + 2 * (size_t)E_ * E_, ipb + 2 * E_, v16, B_ * S1_, E_, E_, S1_, S1_);
    // 6. attention -> ctx (B,H,E) fp32, aliases cond
    attn_kernel<<<(B_ * NH_ * H_) / 4, 256, 0, stream>>>(q16, k16, v16, bt, ctxB);
    // 7. out projection -> ctxo (B,H,E) fp32, aliases q16 region
    gemm_wt<false, float><<<dim3(E_ / 64, (B_ * H_) / 64), blk, 0, stream>>>(
        ctxB, out_W, out_b, ctxoB, B_ * H_, E_, E_, H_, H_);
    // 8. ctx residual + FiLM scale -> out
    final_kernel<<<dim3(H_ / 64, C_ / 64, B_), blk, 0, stream>>>(
        ctxoB, ctx_W, ctx_b, x, scaleB, out);
}

// Round 3
// 1022.572 us; speedup vs baseline: 5.5466x; 5.5466x over previous
//
#include <hip/hip_runtime.h>
#include <cmath>

#define B_  16
#define C_  256
#define H_  1024
#define S_  1024
#define E_  512
#define NH_ 8
#define DD_ 512
#define DS_ 64
#define HD_ 64
#define S1_ 1025
#define RELM 2048

#define BK 16
#define BM 64
#define BN 64
#define PAD 68   // padded LDS row (68 floats): float4-aligned, 2-way banks only (free on gfx950)

typedef __attribute__((ext_vector_type(8))) short bf16x8;
typedef __attribute__((ext_vector_type(4))) float f32x4;

__device__ __forceinline__ unsigned short f2bf(float f) {
    unsigned u = __float_as_uint(f);
    u += 0x7fffu + ((u >> 16) & 1u);   // RNE
    return (unsigned short)(u >> 16);
}
__device__ __forceinline__ float bf2f(unsigned short h) {
    return __uint_as_float((unsigned)h << 16);
}

// C[m,n] = sum_k A[m,k] * W[n,k] + bias[n]
// !ATRANS: A row-major (M,K). ATRANS: A[m,k] at (m/rpb_in)*(K*rpb_in) + k*rpb_in + (m%rpb_in)
// out row remap: orow = (m/rpb_in)*rpb_out + m%rpb_in.  OutT: float or unsigned short (bf16)
template<bool ATRANS, typename OutT>
__global__ __launch_bounds__(256)
void gemm_wt(const float* __restrict__ A, const float* __restrict__ W,
             const float* __restrict__ bias, OutT* __restrict__ Cmat,
             int M, int N, int K, int rpb_in, int rpb_out)
{
    __shared__ float As[BK][PAD];
    __shared__ float Ws[BK][PAD];
    const int tx = threadIdx.x, ty = threadIdx.y;
    const int tid = ty * 16 + tx;
    const int m0 = blockIdx.y * BM;
    const int n0 = blockIdx.x * BN;
    float acc[4][4] = {};
    for (int k0 = 0; k0 < K; k0 += BK) {
        if constexpr (!ATRANS) {
            int c = tid & 15, r = tid >> 4;
#pragma unroll
            for (int i = 0; i < 4; i++) {
                int m = m0 + r + i * 16;
                As[c][r + i * 16] = (m < M) ? A[(size_t)m * K + k0 + c] : 0.f;
            }
        } else {
            int h = tid & 63, kt = tid >> 6;
            int bb = m0 / rpb_in;
            int hbase = m0 % rpb_in;
            const float* Ab = A + (size_t)bb * K * rpb_in + hbase + h;
#pragma unroll
            for (int i = 0; i < 4; i++) {
                int k = k0 + kt + i * 4;
                As[kt + i * 4][h] = Ab[(size_t)k * rpb_in];
            }
        }
        {
            int c = tid & 15, r = tid >> 4;
#pragma unroll
            for (int i = 0; i < 4; i++) {
                int n = n0 + r + i * 16;
                Ws[c][r + i * 16] = W[(size_t)n * K + k0 + c];
            }
        }
        __syncthreads();
#pragma unroll
        for (int kk = 0; kk < BK; kk++) {
            float4 a4 = *(const float4*)&As[kk][ty * 4];
            float4 w4 = *(const float4*)&Ws[kk][tx * 4];
            float av[4] = {a4.x, a4.y, a4.z, a4.w};
            float wv[4] = {w4.x, w4.y, w4.z, w4.w};
#pragma unroll
            for (int i = 0; i < 4; i++)
#pragma unroll
                for (int j = 0; j < 4; j++)
                    acc[i][j] += av[i] * wv[j];
        }
        __syncthreads();
    }
#pragma unroll
    for (int i = 0; i < 4; i++) {
        int m = m0 + ty * 4 + i;
        if (m < M) {
            int orow = (m / rpb_in) * rpb_out + (m % rpb_in);
            const float* bp = bias + n0 + tx * 4;
            if constexpr (sizeof(OutT) == 2) {
                unsigned short* cp = (unsigned short*)Cmat + (size_t)orow * N + n0 + tx * 4;
                ushort4 pk;
                pk.x = f2bf(acc[i][0] + bp[0]);
                pk.y = f2bf(acc[i][1] + bp[1]);
                pk.z = f2bf(acc[i][2] + bp[2]);
                pk.w = f2bf(acc[i][3] + bp[3]);
                *(ushort4*)cp = pk;
            } else {
                float* cp = (float*)Cmat + (size_t)orow * N + n0 + tx * 4;
#pragma unroll
                for (int j = 0; j < 4; j++)
                    cp[j] = acc[i][j] + bp[j];
            }
        }
    }
}

// WqW[e,c] = sum_k ipW[e,k] * q_W[k,c];  qb2[e] = sum_k ipW[e,k]*q_b[k] + ipb[e]
__global__ __launch_bounds__(256)
void fuse_qw_kernel(const float* __restrict__ ipW, const float* __restrict__ ipb,
                    const float* __restrict__ q_W, const float* __restrict__ q_b,
                    float* __restrict__ WqW, float* __restrict__ qb2)
{
    const int e = blockIdx.x;
    const int c = threadIdx.x;
    const float* wrow = ipW + (size_t)e * E_;
    float acc = 0.f;
    for (int k = 0; k < E_; k++) acc += wrow[k] * q_W[(size_t)k * C_ + c];
    WqW[(size_t)e * C_ + c] = acc;
    __shared__ float red[256];
    float bacc = 0.f;
    for (int k = c; k < E_; k += 256) bacc += wrow[k] * q_b[k];
    red[c] = bacc;
    __syncthreads();
    for (int s = 128; s > 0; s >>= 1) {
        if (c < s) red[c] += red[c + s];
        __syncthreads();
    }
    if (c == 0) qb2[e] = red[0] + ipb[e];
}

// static token + FiLM MLP; writes static row into cond buffer; scale = 1 + tanh(film)
__global__ __launch_bounds__(256)
void static_film_kernel(const float* __restrict__ statIn,
                        const float* __restrict__ stat_W, const float* __restrict__ stat_b,
                        const float* __restrict__ fW1, const float* __restrict__ fb1,
                        const float* __restrict__ fW2, const float* __restrict__ fb2,
                        float* __restrict__ cond, float* __restrict__ scaleOut)
{
    __shared__ float s_sh[DS_];
    __shared__ float st_sh[E_];
    __shared__ float h1_sh[E_];
    const int b = blockIdx.x, t = threadIdx.x;
    if (t < DS_) s_sh[t] = statIn[b * DS_ + t];
    __syncthreads();
    for (int e = t; e < E_; e += 256) {
        float acc = stat_b[e];
#pragma unroll 4
        for (int j = 0; j < DS_; j++) acc += s_sh[j] * stat_W[e * DS_ + j];
        st_sh[e] = acc;
        cond[((size_t)(b * S1_ + S_)) * E_ + e] = acc;
    }
    __syncthreads();
    for (int e = t; e < E_; e += 256) {
        float acc = fb1[e];
#pragma unroll 4
        for (int j = 0; j < E_; j++) acc += st_sh[j] * fW1[(size_t)e * E_ + j];
        h1_sh[e] = (acc >= 0.f) ? acc : 0.1f * acc;
    }
    __syncthreads();
    for (int c = t; c < C_; c += 256) {
        float acc = fb2[c];
#pragma unroll 4
        for (int j = 0; j < E_; j++) acc += h1_sh[j] * fW2[(size_t)c * E_ + j];
        scaleOut[b * C_ + c] = 1.f + tanhf(acc);
    }
}

// ---- MFMA flash attention ----
// block = (b, nh, 64-query tile); 4 waves x 16 queries. K-loop over 32-key tiles.
// Scores tiny (|s*scale+bias| << 1): plain exp, unnormalized accumulate, final divide.
// Layouts (m89/m91-verified): C/D row=(lane>>4)*4+reg, col=lane&15;
//   A[m=lane&15][k=(lane>>4)*8+j]; B[k=(lane>>4)*8+j][n=lane&15].
#define KSTRIDE 72   // bf16/row: 144 B, 16B-aligned b128 rows, 2-way banks (free)
#define VSTRIDE 76   // 152 B: quad-term 304 dwords % 32 = 16 -> 2-way on scalar reads
#define PSTRIDE 40   // 80 B: b128-aligned A-frag rows, 2-way banks

__global__ __launch_bounds__(256)
void attn_mfma_kernel(const unsigned short* __restrict__ q,
                      const unsigned short* __restrict__ k,
                      const unsigned short* __restrict__ v,
                      const float* __restrict__ bt,
                      float* __restrict__ ctx)
{
    const int blk  = blockIdx.x;
    const int qblk = blk & 15;           // H/64 = 16
    const int nh   = (blk >> 4) & 7;
    const int b    = blk >> 7;
    const int q0blk = qblk * 64;
    const int tid  = threadIdx.x;
    const int wave = tid >> 6;
    const int lane = tid & 63;
    const int quad = lane >> 4;
    const int l15  = lane & 15;
    const int q0w  = q0blk + wave * 16;

    __shared__ unsigned short Kt[32 * KSTRIDE];
    __shared__ unsigned short Vt[32 * VSTRIDE];
    __shared__ unsigned short Pt[4][16 * PSTRIDE];

    // Q A-fragments (d-chunks 0..31, 32..63), straight from global
    const unsigned short* qrow = q + ((size_t)(b * H_ + q0w + l15)) * E_ + nh * HD_;
    const bf16x8 qa0 = *(const bf16x8*)(qrow + quad * 8);
    const bf16x8 qa1 = *(const bf16x8*)(qrow + 32 + quad * 8);

    bf16x8 ones;
#pragma unroll
    for (int j = 0; j < 8; j++) ((short*)&ones)[j] = (short)0x3F80;  // bf16 1.0

    f32x4 o0 = {0,0,0,0}, o1 = {0,0,0,0}, o2 = {0,0,0,0}, o3 = {0,0,0,0};
    f32x4 lfrag = {0,0,0,0};

    const int srow = tid >> 3;          // staging: 32 rows x (8 thr x 8 el)
    const int scol = (tid & 7) * 8;
    const int ntiles = 2 * qblk + 3;    // causal tiles + static tile

    for (int t = 0; t < ntiles; t++) {
        const int k0 = (t == ntiles - 1) ? 1024 : t * 32;
        __syncthreads();
        {   // stage K,V tile (rows k0..k0+31; buffers padded so reads are in-bounds)
            const size_t gk = ((size_t)(b * S1_) + k0 + srow) * E_ + nh * HD_ + scol;
            *(bf16x8*)&Kt[srow * KSTRIDE + scol] = *(const bf16x8*)(k + gk);
            *(ushort4*)&Vt[srow * VSTRIDE + scol]     = *(const ushort4*)(v + gk);
            *(ushort4*)&Vt[srow * VSTRIDE + scol + 4] = *(const ushort4*)(v + gk + 4);
        }
        __syncthreads();

        // S = Q K^T : two 16-key fragments
        f32x4 s0 = {0,0,0,0}, s1 = {0,0,0,0};
        {
            bf16x8 kb;
            kb = *(const bf16x8*)&Kt[l15 * KSTRIDE + quad * 8];
            s0 = __builtin_amdgcn_mfma_f32_16x16x32_bf16(qa0, kb, s0, 0, 0, 0);
            kb = *(const bf16x8*)&Kt[l15 * KSTRIDE + 32 + quad * 8];
            s0 = __builtin_amdgcn_mfma_f32_16x16x32_bf16(qa1, kb, s0, 0, 0, 0);
            kb = *(const bf16x8*)&Kt[(16 + l15) * KSTRIDE + quad * 8];
            s1 = __builtin_amdgcn_mfma_f32_16x16x32_bf16(qa0, kb, s1, 0, 0, 0);
            kb = *(const bf16x8*)&Kt[(16 + l15) * KSTRIDE + 32 + quad * 8];
            s1 = __builtin_amdgcn_mfma_f32_16x16x32_bf16(qa1, kb, s1, 0, 0, 0);
        }

        // bias + causal mask + exp, write P (bf16) to this wave's LDS region
        unsigned short* pw = Pt[wave];
#pragma unroll
        for (int f = 0; f < 2; f++) {
            const int kk = k0 + f * 16 + l15;
#pragma unroll
            for (int r = 0; r < 4; r++) {
                const int qi = q0w + quad * 4 + r;
                const bool vis = (kk <= qi) || (kk == 1024);
                const float sv = f ? s1[r] : s0[r];
                const float pp = vis ? __expf(sv * 0.125f + bt[qi - kk + (RELM - 1)]) : 0.f;
                pw[(quad * 4 + r) * PSTRIDE + f * 16 + l15] = f2bf(pp);
            }
        }
        // wave-internal LDS round-trip (compiler inserts lgkmcnt wait)
        const bf16x8 pa = *(const bf16x8*)&pw[l15 * PSTRIDE + quad * 8];

        // l += P @ ones ; O += P @ V
        lfrag = __builtin_amdgcn_mfma_f32_16x16x32_bf16(pa, ones, lfrag, 0, 0, 0);
#pragma unroll
        for (int dt = 0; dt < 4; dt++) {
            bf16x8 vb;
#pragma unroll
            for (int j = 0; j < 8; j++)
                ((short*)&vb)[j] = (short)Vt[(quad * 8 + j) * VSTRIDE + dt * 16 + l15];
            f32x4& od = dt == 0 ? o0 : dt == 1 ? o1 : dt == 2 ? o2 : o3;
            od = __builtin_amdgcn_mfma_f32_16x16x32_bf16(pa, vb, od, 0, 0, 0);
        }
    }

    // epilogue: normalize and store; l row mapping == O row mapping
    float* crow = ctx + ((size_t)(b * H_ + q0w + quad * 4)) * E_ + nh * HD_ + l15;
#pragma unroll
    for (int r = 0; r < 4; r++) {
        const float inv = 1.f / lfrag[r];
        crow[(size_t)r * E_ + 0]  = o0[r] * inv;
        crow[(size_t)r * E_ + 16] = o1[r] * inv;
        crow[(size_t)r * E_ + 32] = o2[r] * inv;
        crow[(size_t)r * E_ + 48] = o3[r] * inv;
    }
}

// out[b,c,h] = (x[b,c,h] + sum_e ctxo[b,h,e]*ctx_W[c,e] + ctx_b[c]) * scale[b,c]
__global__ __launch_bounds__(256)
void final_kernel(const float* __restrict__ ctxo, const float* __restrict__ ctx_W,
                  const float* __restrict__ ctx_b, const float* __restrict__ x,
                  const float* __restrict__ scale, float* __restrict__ out)
{
    __shared__ float Asm[BK][PAD];
    __shared__ float Bsm[BK][PAD];
    const int tx = threadIdx.x, ty = threadIdx.y;
    const int tid = ty * 16 + tx;
    const int b = blockIdx.z;
    const int c0 = blockIdx.y * 64;
    const int h0 = blockIdx.x * 64;
    float acc[4][4] = {};
    for (int e0 = 0; e0 < E_; e0 += BK) {
        int ee = tid & 15, r = tid >> 4;
#pragma unroll
        for (int i = 0; i < 4; i++) {
            Asm[ee][r + i * 16] = ctx_W[(size_t)(c0 + r + i * 16) * E_ + e0 + ee];
            Bsm[ee][r + i * 16] = ctxo[((size_t)b * H_ + h0 + r + i * 16) * E_ + e0 + ee];
        }
        __syncthreads();
#pragma unroll
        for (int kk = 0; kk < BK; kk++) {
            float4 a4 = *(const float4*)&Asm[kk][ty * 4];
            float4 b4 = *(const float4*)&Bsm[kk][tx * 4];
            float av[4] = {a4.x, a4.y, a4.z, a4.w};
            float bv[4] = {b4.x, b4.y, b4.z, b4.w};
#pragma unroll
            for (int i = 0; i < 4; i++)
#pragma unroll
                for (int j = 0; j < 4; j++)
                    acc[i][j] += av[i] * bv[j];
        }
        __syncthreads();
    }
#pragma unroll
    for (int i = 0; i < 4; i++) {
        int c = c0 + ty * 4 + i;
        float sc = scale[b * C_ + c];
        float cb = ctx_b[c];
        const float* xp = x + ((size_t)b * C_ + c) * H_ + h0 + tx * 4;
        float* op = out + ((size_t)b * C_ + c) * H_ + h0 + tx * 4;
#pragma unroll
        for (int j = 0; j < 4; j++)
            op[j] = (xp[j] + acc[i][j] + cb) * sc;
    }
}

extern "C" void kernel_launch(void* const* d_in, const int* in_sizes, int n_in,
                              void* d_out, int out_size, void* d_ws, size_t ws_size,
                              hipStream_t stream)
{
    (void)in_sizes; (void)n_in; (void)out_size; (void)ws_size;
    const float* x      = (const float*)d_in[0];
    const float* dyn    = (const float*)d_in[1];
    const float* statIn = (const float*)d_in[2];
    const float* dyn_W  = (const float*)d_in[3];
    const float* dyn_b  = (const float*)d_in[4];
    const float* stat_W = (const float*)d_in[5];
    const float* stat_b = (const float*)d_in[6];
    const float* fW1    = (const float*)d_in[7];
    const float* fb1    = (const float*)d_in[8];
    const float* fW2    = (const float*)d_in[9];
    const float* fb2    = (const float*)d_in[10];
    const float* q_W    = (const float*)d_in[11];
    const float* q_b    = (const float*)d_in[12];
    const float* ipW    = (const float*)d_in[13];
    const float* ipb    = (const float*)d_in[14];
    const float* out_W  = (const float*)d_in[15];
    const float* out_b  = (const float*)d_in[16];
    const float* ctx_W  = (const float*)d_in[17];
    const float* ctx_b  = (const float*)d_in[18];
    const float* bt     = (const float*)d_in[19];
    float* out = (float*)d_out;

    // ---- workspace layout (~84.6 MB) ----
    char* w = (char*)d_ws;
    size_t off = 0;
    float* cond   = (float*)(w + off); off += (size_t)B_ * S1_ * E_ * 4;
    float* scaleB = (float*)(w + off); off += (size_t)B_ * C_ * 4;
    float* WqW    = (float*)(w + off); off += (size_t)E_ * C_ * 4;
    float* qb2    = (float*)(w + off); off += E_ * 4;
    unsigned short* q16 = (unsigned short*)(w + off);
    unsigned short* k16 = q16 + (size_t)B_ * H_ * E_;
    unsigned short* v16 = k16 + ((size_t)B_ * S1_ + 32) * E_;   // +32 pad rows for tile reads
    // aliases over dead regions:
    float* ctxB  = cond;           // cond dead after K/V projections
    float* ctxoB = (float*)q16;    // q16/k16 dead after attention

    dim3 blk(16, 16);
    // 1. dyn_tokens -> cond rows [b*S1 + s]  (fp32)
    gemm_wt<false, float><<<dim3(E_ / 64, (B_ * S_) / 64), blk, 0, stream>>>(
        dyn, dyn_W, dyn_b, cond, B_ * S_, E_, DD_, S_, S1_);
    // 2. static token (into cond row b*S1+S) + FiLM scale
    static_film_kernel<<<B_, 256, 0, stream>>>(statIn, stat_W, stat_b, fW1, fb1, fW2, fb2,
                                               cond, scaleB);
    // 3. fused query weight: WqW = Wq @ q_W, qb2 = Wq @ q_b + bq
    fuse_qw_kernel<<<E_, C_, 0, stream>>>(ipW, ipb, q_W, q_b, WqW, qb2);
    // 4. q[b,h,e] = sum_c x[b,c,h]*WqW[e,c] + qb2[e]  -> bf16
    gemm_wt<true, unsigned short><<<dim3(E_ / 64, (B_ * H_) / 64), blk, 0, stream>>>(
        x, WqW, qb2, q16, B_ * H_, E_, C_, H_, H_);
    // 5. k / v projections -> bf16
    gemm_wt<false, unsigned short><<<dim3(E_ / 64, (B_ * S1_ + 63) / 64), blk, 0, stream>>>(
        cond, ipW + (size_t)E_ * E_, ipb + E_, k16, B_ * S1_, E_, E_, S1_, S1_);
    gemm_wt<false, unsigned short><<<dim3(E_ / 64, (B_ * S1_ + 63) / 64), blk, 0, stream>>>(
        cond, ipW + 2 * (size_t)E_ * E_, ipb + 2 * E_, v16, B_ * S1_, E_, E_, S1_, S1_);
    // 6. MFMA flash attention -> ctx (B,H,E) fp32, aliases cond
    attn_mfma_kernel<<<B_ * NH_ * (H_ / 64), 256, 0, stream>>>(q16, k16, v16, bt, ctxB);
    // 7. out projection -> ctxo (B,H,E) fp32, aliases q16 region
    gemm_wt<false, float><<<dim3(E_ / 64, (B_ * H_) / 64), blk, 0, stream>>>(
        ctxB, out_W, out_b, ctxoB, B_ * H_, E_, E_, H_, H_);
    // 8. ctx residual + FiLM scale -> out
    final_kernel<<<dim3(H_ / 64, C_ / 64, B_), blk, 0, stream>>>(
        ctxoB, ctx_W, ctx_b, x, scaleB, out);
}

// Round 4
// 478.921 us; speedup vs baseline: 11.8429x; 2.1352x over previous
//
#include <hip/hip_runtime.h>
#include <cmath>

#define B_  16
#define C_  256
#define H_  1024
#define S_  1024
#define E_  512
#define NH_ 8
#define DD_ 512
#define DS_ 64
#define HD_ 64
#define S1_ 1025
#define RELM 2048

typedef __attribute__((ext_vector_type(8))) short bf16x8;
typedef __attribute__((ext_vector_type(4))) float f32x4;

__device__ __forceinline__ unsigned short f2bf(float f) {
    unsigned u = __float_as_uint(f);
    u += 0x7fffu + ((u >> 16) & 1u);   // RNE
    return (unsigned short)(u >> 16);
}
__device__ __forceinline__ float bf2f(unsigned short h) {
    return __uint_as_float((unsigned)h << 16);
}

// async global->LDS, 16B per lane; LDS dest = wave-uniform base + lane*16 (m97 pattern)
__device__ __forceinline__ void gl2lds16(const unsigned short* g, unsigned short* l) {
#if __has_builtin(__builtin_amdgcn_global_load_lds)
    __builtin_amdgcn_global_load_lds(
        (const __attribute__((address_space(1))) void*)g,
        (__attribute__((address_space(3))) void*)l, 16, 0, 0);
#else
    const int ln = threadIdx.x & 63;
    *(bf16x8*)(l + ln * 8) = *(const bf16x8*)g;
#endif
}

// fp32 -> bf16 elementwise, 8 el/thread (n % 8 == 0)
__global__ __launch_bounds__(256)
void conv_bf16(const float* __restrict__ src, unsigned short* __restrict__ dst, int n)
{
    int i = (blockIdx.x * 256 + threadIdx.x) * 8;
    if (i < n) {
        float4 a = *(const float4*)(src + i);
        float4 b = *(const float4*)(src + i + 4);
        bf16x8 o;
        ((unsigned short*)&o)[0] = f2bf(a.x); ((unsigned short*)&o)[1] = f2bf(a.y);
        ((unsigned short*)&o)[2] = f2bf(a.z); ((unsigned short*)&o)[3] = f2bf(a.w);
        ((unsigned short*)&o)[4] = f2bf(b.x); ((unsigned short*)&o)[5] = f2bf(b.y);
        ((unsigned short*)&o)[6] = f2bf(b.z); ((unsigned short*)&o)[7] = f2bf(b.w);
        *(bf16x8*)(dst + i) = o;
    }
}

// xT16[b*H + h][c] = bf16(x[b][c][h])
__global__ __launch_bounds__(256)
void xpose_kernel(const float* __restrict__ x, unsigned short* __restrict__ xT)
{
    __shared__ float t[64][65];
    const int b = blockIdx.z;
    const int h0 = blockIdx.x * 64;
    const int c0 = blockIdx.y * 64;
    const int tx = threadIdx.x & 15;
    const int ty = threadIdx.x >> 4;
#pragma unroll
    for (int i = 0; i < 4; i++) {
        const float4 v = *(const float4*)&x[((size_t)(b * C_ + c0 + ty + i * 16)) * H_ + h0 + tx * 4];
        t[ty + i * 16][tx * 4 + 0] = v.x;
        t[ty + i * 16][tx * 4 + 1] = v.y;
        t[ty + i * 16][tx * 4 + 2] = v.z;
        t[ty + i * 16][tx * 4 + 3] = v.w;
    }
    __syncthreads();
#pragma unroll
    for (int i = 0; i < 4; i++) {
        const int hh = ty + i * 16;
        ushort4 o;
        o.x = f2bf(t[tx * 4 + 0][hh]);
        o.y = f2bf(t[tx * 4 + 1][hh]);
        o.z = f2bf(t[tx * 4 + 2][hh]);
        o.w = f2bf(t[tx * 4 + 3][hh]);
        *(ushort4*)&xT[((size_t)(b * H_ + h0 + hh)) * C_ + c0 + tx * 4] = o;
    }
}

// ---- m97-style bf16 MFMA GEMM: C[m,n] = sum_k A[m,k]*W[n,k] + bias[n] ----
// 128x128 tile, BK=32, 4 waves x (4x4) 16x16x32 frags, global_load_lds staging.
// REMAP: output row (m/1024)*1025 + m%1024 (dyn tokens -> cond rows).
// FINAL: per-batch (blockIdx.z), W = ctxo16 + z*N*K; fp32 out with x/scale/ctx_b fused.
template<bool REMAP, bool FINAL>
__global__ __launch_bounds__(256)
void gemm_mfma(const unsigned short* __restrict__ A, const unsigned short* __restrict__ W,
               const float* __restrict__ bias, void* __restrict__ Cout,
               int M, int N, int K,
               const float* __restrict__ x, const float* __restrict__ scale)
{
    __shared__ unsigned short At[128 * 32];
    __shared__ unsigned short Wt[128 * 32];
    const int tid  = threadIdx.x;
    const int wave = tid >> 6;
    const int lane = tid & 63;
    const int quad = lane >> 4;
    const int l15  = lane & 15;
    const int m0 = blockIdx.y * 128;
    const int n0 = blockIdx.x * 128;
    const int rw = (wave >> 1) * 64;
    const int cw = (wave & 1) * 64;
    const int zb = FINAL ? blockIdx.z : 0;
    const unsigned short* Wb = FINAL ? W + (size_t)zb * N * K : W;

    const int srow = lane >> 2;          // 0..15
    const int scol = (lane & 3) * 8;     // bf16 col within BK

    f32x4 acc[4][4] = {};

    for (int k0 = 0; k0 < K; k0 += 32) {
        __syncthreads();
#pragma unroll
        for (int c = 0; c < 2; c++) {
            const int chunk = wave + c * 4;            // 8 chunks of 16 rows
            const unsigned short* ga = A  + (size_t)(m0 + chunk * 16 + srow) * K + k0 + scol;
            gl2lds16(ga, &At[chunk * 512]);
            const unsigned short* gw = Wb + (size_t)(n0 + chunk * 16 + srow) * K + k0 + scol;
            gl2lds16(gw, &Wt[chunk * 512]);
        }
        __syncthreads();   // drains vmcnt(0): staged data visible
        bf16x8 af[4], wf[4];
#pragma unroll
        for (int i = 0; i < 4; i++)
            af[i] = *(const bf16x8*)&At[(rw + i * 16 + l15) * 32 + quad * 8];
#pragma unroll
        for (int j = 0; j < 4; j++)
            wf[j] = *(const bf16x8*)&Wt[(cw + j * 16 + l15) * 32 + quad * 8];
#pragma unroll
        for (int i = 0; i < 4; i++)
#pragma unroll
            for (int j = 0; j < 4; j++)
                acc[i][j] = __builtin_amdgcn_mfma_f32_16x16x32_bf16(af[i], wf[j], acc[i][j], 0, 0, 0);
    }

    if constexpr (!FINAL) {
        float bias4[4];
#pragma unroll
        for (int j = 0; j < 4; j++) bias4[j] = bias[n0 + cw + j * 16 + l15];
#pragma unroll
        for (int i = 0; i < 4; i++) {
#pragma unroll
            for (int r = 0; r < 4; r++) {
                const int mm = m0 + rw + i * 16 + quad * 4 + r;
                if (mm < M) {
                    const int orow = REMAP ? ((mm >> 10) * S1_ + (mm & 1023)) : mm;
                    unsigned short* cp = (unsigned short*)Cout + (size_t)orow * N + n0 + cw + l15;
#pragma unroll
                    for (int j = 0; j < 4; j++)
                        cp[j * 16] = f2bf(acc[i][j][r] + bias4[j]);
                }
            }
        }
    } else {
#pragma unroll
        for (int i = 0; i < 4; i++) {
#pragma unroll
            for (int r = 0; r < 4; r++) {
                const int mm = m0 + rw + i * 16 + quad * 4 + r;   // c index (M=256)
                const float cb = bias[mm];
                const float sc = scale[zb * C_ + mm];
                const size_t base = ((size_t)(zb * C_ + mm)) * H_ + n0 + cw + l15;
#pragma unroll
                for (int j = 0; j < 4; j++)
                    ((float*)Cout)[base + j * 16] = (x[base + j * 16] + acc[i][j][r] + cb) * sc;
            }
        }
    }
}

// WqW16[e,c] = bf16(sum_k ipW[e,k]*q_W[k,c]);  qb2[e] = sum_k ipW[e,k]*q_b[k] + ipb[e]
__global__ __launch_bounds__(256)
void fuse_qw_kernel(const float* __restrict__ ipW, const float* __restrict__ ipb,
                    const float* __restrict__ q_W, const float* __restrict__ q_b,
                    unsigned short* __restrict__ WqW16, float* __restrict__ qb2)
{
    const int e = blockIdx.x;
    const int c = threadIdx.x;
    const float* wrow = ipW + (size_t)e * E_;
    float acc = 0.f;
    for (int k = 0; k < E_; k++) acc += wrow[k] * q_W[(size_t)k * C_ + c];
    WqW16[(size_t)e * C_ + c] = f2bf(acc);
    __shared__ float red[256];
    float bacc = 0.f;
    for (int k = c; k < E_; k += 256) bacc += wrow[k] * q_b[k];
    red[c] = bacc;
    __syncthreads();
    for (int s = 128; s > 0; s >>= 1) {
        if (c < s) red[c] += red[c + s];
        __syncthreads();
    }
    if (c == 0) qb2[e] = red[0] + ipb[e];
}

// static token + FiLM MLP; writes static row (bf16) into cond16; scale = 1 + tanh(film)
__global__ __launch_bounds__(256)
void static_film_kernel(const float* __restrict__ statIn,
                        const float* __restrict__ stat_W, const float* __restrict__ stat_b,
                        const float* __restrict__ fW1, const float* __restrict__ fb1,
                        const float* __restrict__ fW2, const float* __restrict__ fb2,
                        unsigned short* __restrict__ cond16, float* __restrict__ scaleOut)
{
    __shared__ float s_sh[DS_];
    __shared__ float st_sh[E_];
    __shared__ float h1_sh[E_];
    const int b = blockIdx.x, t = threadIdx.x;
    if (t < DS_) s_sh[t] = statIn[b * DS_ + t];
    __syncthreads();
    for (int e = t; e < E_; e += 256) {
        float acc = stat_b[e];
#pragma unroll 4
        for (int j = 0; j < DS_; j++) acc += s_sh[j] * stat_W[e * DS_ + j];
        st_sh[e] = acc;
        cond16[((size_t)(b * S1_ + S_)) * E_ + e] = f2bf(acc);
    }
    __syncthreads();
    for (int e = t; e < E_; e += 256) {
        float acc = fb1[e];
#pragma unroll 4
        for (int j = 0; j < E_; j++) acc += st_sh[j] * fW1[(size_t)e * E_ + j];
        h1_sh[e] = (acc >= 0.f) ? acc : 0.1f * acc;
    }
    __syncthreads();
    for (int c = t; c < C_; c += 256) {
        float acc = fb2[c];
#pragma unroll 4
        for (int j = 0; j < E_; j++) acc += h1_sh[j] * fW2[(size_t)c * E_ + j];
        scaleOut[b * C_ + c] = 1.f + tanhf(acc);
    }
}

// ---- MFMA flash attention (R3-verified) ----
#define KSTRIDE 72
#define VSTRIDE 76
#define PSTRIDE 40

__global__ __launch_bounds__(256)
void attn_mfma_kernel(const unsigned short* __restrict__ q,
                      const unsigned short* __restrict__ k,
                      const unsigned short* __restrict__ v,
                      const float* __restrict__ bt,
                      unsigned short* __restrict__ ctx)
{
    const int blk  = blockIdx.x;
    const int qblk = blk & 15;
    const int nh   = (blk >> 4) & 7;
    const int b    = blk >> 7;
    const int tid  = threadIdx.x;
    const int wave = tid >> 6;
    const int lane = tid & 63;
    const int quad = lane >> 4;
    const int l15  = lane & 15;
    const int q0w  = qblk * 64 + wave * 16;

    __shared__ unsigned short Kt[32 * KSTRIDE];
    __shared__ unsigned short Vt[32 * VSTRIDE];
    __shared__ unsigned short Pt[4][16 * PSTRIDE];

    const unsigned short* qrow = q + ((size_t)(b * H_ + q0w + l15)) * E_ + nh * HD_;
    const bf16x8 qa0 = *(const bf16x8*)(qrow + quad * 8);
    const bf16x8 qa1 = *(const bf16x8*)(qrow + 32 + quad * 8);

    bf16x8 ones;
#pragma unroll
    for (int j = 0; j < 8; j++) ((short*)&ones)[j] = (short)0x3F80;

    f32x4 o0 = {0,0,0,0}, o1 = {0,0,0,0}, o2 = {0,0,0,0}, o3 = {0,0,0,0};
    f32x4 lfrag = {0,0,0,0};

    const int srow = tid >> 3;
    const int scol = (tid & 7) * 8;
    const int ntiles = 2 * qblk + 3;

    for (int t = 0; t < ntiles; t++) {
        const int k0 = (t == ntiles - 1) ? 1024 : t * 32;
        __syncthreads();
        {
            const size_t gk = ((size_t)(b * S1_) + k0 + srow) * E_ + nh * HD_ + scol;
            *(bf16x8*)&Kt[srow * KSTRIDE + scol] = *(const bf16x8*)(k + gk);
            *(ushort4*)&Vt[srow * VSTRIDE + scol]     = *(const ushort4*)(v + gk);
            *(ushort4*)&Vt[srow * VSTRIDE + scol + 4] = *(const ushort4*)(v + gk + 4);
        }
        __syncthreads();

        f32x4 s0 = {0,0,0,0}, s1 = {0,0,0,0};
        {
            bf16x8 kb;
            kb = *(const bf16x8*)&Kt[l15 * KSTRIDE + quad * 8];
            s0 = __builtin_amdgcn_mfma_f32_16x16x32_bf16(qa0, kb, s0, 0, 0, 0);
            kb = *(const bf16x8*)&Kt[l15 * KSTRIDE + 32 + quad * 8];
            s0 = __builtin_amdgcn_mfma_f32_16x16x32_bf16(qa1, kb, s0, 0, 0, 0);
            kb = *(const bf16x8*)&Kt[(16 + l15) * KSTRIDE + quad * 8];
            s1 = __builtin_amdgcn_mfma_f32_16x16x32_bf16(qa0, kb, s1, 0, 0, 0);
            kb = *(const bf16x8*)&Kt[(16 + l15) * KSTRIDE + 32 + quad * 8];
            s1 = __builtin_amdgcn_mfma_f32_16x16x32_bf16(qa1, kb, s1, 0, 0, 0);
        }

        unsigned short* pw = Pt[wave];
#pragma unroll
        for (int f = 0; f < 2; f++) {
            const int kk = k0 + f * 16 + l15;
#pragma unroll
            for (int r = 0; r < 4; r++) {
                const int qi = q0w + quad * 4 + r;
                const bool vis = (kk <= qi) || (kk == 1024);
                const float sv = f ? s1[r] : s0[r];
                const float pp = vis ? __expf(sv * 0.125f + bt[qi - kk + (RELM - 1)]) : 0.f;
                pw[(quad * 4 + r) * PSTRIDE + f * 16 + l15] = f2bf(pp);
            }
        }
        const bf16x8 pa = *(const bf16x8*)&pw[l15 * PSTRIDE + quad * 8];

        lfrag = __builtin_amdgcn_mfma_f32_16x16x32_bf16(pa, ones, lfrag, 0, 0, 0);
#pragma unroll
        for (int dt = 0; dt < 4; dt++) {
            bf16x8 vb;
#pragma unroll
            for (int j = 0; j < 8; j++)
                ((short*)&vb)[j] = (short)Vt[(quad * 8 + j) * VSTRIDE + dt * 16 + l15];
            f32x4& od = dt == 0 ? o0 : dt == 1 ? o1 : dt == 2 ? o2 : o3;
            od = __builtin_amdgcn_mfma_f32_16x16x32_bf16(pa, vb, od, 0, 0, 0);
        }
    }

    unsigned short* crow = ctx + ((size_t)(b * H_ + q0w + quad * 4)) * E_ + nh * HD_ + l15;
#pragma unroll
    for (int r = 0; r < 4; r++) {
        const float inv = 1.f / lfrag[r];
        crow[(size_t)r * E_ + 0]  = f2bf(o0[r] * inv);
        crow[(size_t)r * E_ + 16] = f2bf(o1[r] * inv);
        crow[(size_t)r * E_ + 32] = f2bf(o2[r] * inv);
        crow[(size_t)r * E_ + 48] = f2bf(o3[r] * inv);
    }
}

extern "C" void kernel_launch(void* const* d_in, const int* in_sizes, int n_in,
                              void* d_out, int out_size, void* d_ws, size_t ws_size,
                              hipStream_t stream)
{
    (void)in_sizes; (void)n_in; (void)out_size; (void)ws_size;
    const float* x      = (const float*)d_in[0];
    const float* dyn    = (const float*)d_in[1];
    const float* statIn = (const float*)d_in[2];
    const float* dyn_W  = (const float*)d_in[3];
    const float* dyn_b  = (const float*)d_in[4];
    const float* stat_W = (const float*)d_in[5];
    const float* stat_b = (const float*)d_in[6];
    const float* fW1    = (const float*)d_in[7];
    const float* fb1    = (const float*)d_in[8];
    const float* fW2    = (const float*)d_in[9];
    const float* fb2    = (const float*)d_in[10];
    const float* q_W    = (const float*)d_in[11];
    const float* q_b    = (const float*)d_in[12];
    const float* ipW    = (const float*)d_in[13];
    const float* ipb    = (const float*)d_in[14];
    const float* out_W  = (const float*)d_in[15];
    const float* out_b  = (const float*)d_in[16];
    const float* ctx_W  = (const float*)d_in[17];
    const float* ctx_b  = (const float*)d_in[18];
    const float* bt     = (const float*)d_in[19];
    float* out = (float*)d_out;

    // ---- workspace layout, bf16-heavy, ~78.4 MB (<84.6 proven safe) ----
    const size_t CND_ROWS = 16512;                 // B*S1=16400, padded to 129*128
    char* w = (char*)d_ws; size_t off = 0;
    unsigned short* cond16 = (unsigned short*)(w + off); off += CND_ROWS * E_ * 2;          // 16.9 MB
    unsigned short* k16    = (unsigned short*)(w + off); off += CND_ROWS * E_ * 2;          // 16.9 MB
    unsigned short* v16    = (unsigned short*)(w + off); off += CND_ROWS * E_ * 2;          // 16.9 MB
    unsigned short* dyn16  = (unsigned short*)(w + off); off += (size_t)B_ * S_ * DD_ * 2;  // 16.8 MB
    unsigned short* xT16   = (unsigned short*)(w + off); off += (size_t)B_ * H_ * C_ * 2;   // 8.4 MB
    unsigned short* dynW16 = (unsigned short*)(w + off); off += (size_t)E_ * DD_ * 2;
    unsigned short* ipWk16 = (unsigned short*)(w + off); off += (size_t)E_ * E_ * 2;
    unsigned short* ipWv16 = (unsigned short*)(w + off); off += (size_t)E_ * E_ * 2;
    unsigned short* outW16 = (unsigned short*)(w + off); off += (size_t)E_ * E_ * 2;
    unsigned short* ctxW16 = (unsigned short*)(w + off); off += (size_t)C_ * E_ * 2;
    unsigned short* WqW16  = (unsigned short*)(w + off); off += (size_t)E_ * C_ * 2;
    float* scaleB = (float*)(w + off); off += (size_t)B_ * C_ * 4;
    float* qb2    = (float*)(w + off); off += E_ * 4;
    // aliases over dead regions:
    unsigned short* q16    = dyn16;     // dyn dead after dyn-GEMM
    unsigned short* ctx16  = cond16;    // cond dead after K/V GEMMs
    unsigned short* ctxo16 = dyn16;     // q dead after attention

    // 1. bf16 conversions (weights + dyn)
    conv_bf16<<<(E_ * DD_ / 8 + 255) / 256, 256, 0, stream>>>(dyn_W, dynW16, E_ * DD_);
    conv_bf16<<<(E_ * E_ / 8 + 255) / 256, 256, 0, stream>>>(ipW + (size_t)E_ * E_, ipWk16, E_ * E_);
    conv_bf16<<<(E_ * E_ / 8 + 255) / 256, 256, 0, stream>>>(ipW + 2 * (size_t)E_ * E_, ipWv16, E_ * E_);
    conv_bf16<<<(E_ * E_ / 8 + 255) / 256, 256, 0, stream>>>(out_W, outW16, E_ * E_);
    conv_bf16<<<(C_ * E_ / 8 + 255) / 256, 256, 0, stream>>>(ctx_W, ctxW16, C_ * E_);
    conv_bf16<<<(B_ * S_ * DD_ / 8 + 255) / 256, 256, 0, stream>>>(dyn, dyn16, B_ * S_ * DD_);
    // 2. fused query weight (bf16) + bias
    fuse_qw_kernel<<<E_, C_, 0, stream>>>(ipW, ipb, q_W, q_b, WqW16, qb2);
    // 3. x transpose -> xT16[b*H+h][c]
    xpose_kernel<<<dim3(H_ / 64, C_ / 64, B_), 256, 0, stream>>>(x, xT16);
    // 4. dyn tokens -> cond16 (row remap 1024->1025)
    gemm_mfma<true, false><<<dim3(E_ / 128, B_ * S_ / 128), 256, 0, stream>>>(
        dyn16, dynW16, dyn_b, cond16, B_ * S_, E_, DD_, nullptr, nullptr);
    // 5. static token row + FiLM scale
    static_film_kernel<<<B_, 256, 0, stream>>>(statIn, stat_W, stat_b, fW1, fb1, fW2, fb2,
                                               cond16, scaleB);
    // 6. q = xT @ WqW^T + qb2 -> q16
    gemm_mfma<false, false><<<dim3(E_ / 128, B_ * H_ / 128), 256, 0, stream>>>(
        xT16, WqW16, qb2, q16, B_ * H_, E_, C_, nullptr, nullptr);
    // 7. k / v projections (M=16400 -> 129 row-blocks; A padded)
    gemm_mfma<false, false><<<dim3(E_ / 128, 129), 256, 0, stream>>>(
        cond16, ipWk16, ipb + E_, k16, B_ * S1_, E_, E_, nullptr, nullptr);
    gemm_mfma<false, false><<<dim3(E_ / 128, 129), 256, 0, stream>>>(
        cond16, ipWv16, ipb + 2 * E_, v16, B_ * S1_, E_, E_, nullptr, nullptr);
    // 8. flash attention -> ctx16 (over cond region)
    attn_mfma_kernel<<<B_ * NH_ * (H_ / 64), 256, 0, stream>>>(q16, k16, v16, bt, ctx16);
    // 9. out projection -> ctxo16 (over dyn/q region)
    gemm_mfma<false, false><<<dim3(E_ / 128, B_ * H_ / 128), 256, 0, stream>>>(
        ctx16, outW16, out_b, ctxo16, B_ * H_, E_, E_, nullptr, nullptr);
    // 10. final: per-batch C=ctx_W @ ctxo^T, fused x + ctx_b + FiLM scale -> out (fp32)
    gemm_mfma<false, true><<<dim3(H_ / 128, C_ / 128, B_), 256, 0, stream>>>(
        ctxW16, ctxo16, ctx_b, out, C_, H_, E_, x, scaleB);
}

// Round 5
// 428.386 us; speedup vs baseline: 13.2400x; 1.1180x over previous
//
#include <hip/hip_runtime.h>
#include <cmath>

#define B_  16
#define C_  256
#define H_  1024
#define S_  1024
#define E_  512
#define NH_ 8
#define DD_ 512
#define DS_ 64
#define HD_ 64
#define S1_ 1025
#define RELM 2048

typedef __attribute__((ext_vector_type(8))) short bf16x8;
typedef __attribute__((ext_vector_type(4))) float f32x4;

__device__ __forceinline__ unsigned short f2bf(float f) {
    unsigned u = __float_as_uint(f);
    u += 0x7fffu + ((u >> 16) & 1u);   // RNE
    return (unsigned short)(u >> 16);
}
__device__ __forceinline__ float bf2f(unsigned short h) {
    return __uint_as_float((unsigned)h << 16);
}

// async global->LDS, 16B per lane; LDS dest = wave-uniform base + lane*16 (m97 pattern)
__device__ __forceinline__ void gl2lds16(const unsigned short* g, unsigned short* l) {
#if __has_builtin(__builtin_amdgcn_global_load_lds)
    __builtin_amdgcn_global_load_lds(
        (const __attribute__((address_space(1))) void*)g,
        (__attribute__((address_space(3))) void*)l, 16, 0, 0);
#else
    const int ln = threadIdx.x & 63;
    *(bf16x8*)(l + ln * 8) = *(const bf16x8*)g;
#endif
}

// fp32 -> bf16 elementwise, 8 el/thread (n % 8 == 0)
__global__ __launch_bounds__(256)
void conv_bf16(const float* __restrict__ src, unsigned short* __restrict__ dst, int n)
{
    int i = (blockIdx.x * 256 + threadIdx.x) * 8;
    if (i < n) {
        float4 a = *(const float4*)(src + i);
        float4 b = *(const float4*)(src + i + 4);
        bf16x8 o;
        ((unsigned short*)&o)[0] = f2bf(a.x); ((unsigned short*)&o)[1] = f2bf(a.y);
        ((unsigned short*)&o)[2] = f2bf(a.z); ((unsigned short*)&o)[3] = f2bf(a.w);
        ((unsigned short*)&o)[4] = f2bf(b.x); ((unsigned short*)&o)[5] = f2bf(b.y);
        ((unsigned short*)&o)[6] = f2bf(b.z); ((unsigned short*)&o)[7] = f2bf(b.w);
        *(bf16x8*)(dst + i) = o;
    }
}

// xT16[b*H + h][c] = bf16(x[b][c][h])
__global__ __launch_bounds__(256)
void xpose_kernel(const float* __restrict__ x, unsigned short* __restrict__ xT)
{
    __shared__ float t[64][65];
    const int b = blockIdx.z;
    const int h0 = blockIdx.x * 64;
    const int c0 = blockIdx.y * 64;
    const int tx = threadIdx.x & 15;
    const int ty = threadIdx.x >> 4;
#pragma unroll
    for (int i = 0; i < 4; i++) {
        const float4 v = *(const float4*)&x[((size_t)(b * C_ + c0 + ty + i * 16)) * H_ + h0 + tx * 4];
        t[ty + i * 16][tx * 4 + 0] = v.x;
        t[ty + i * 16][tx * 4 + 1] = v.y;
        t[ty + i * 16][tx * 4 + 2] = v.z;
        t[ty + i * 16][tx * 4 + 3] = v.w;
    }
    __syncthreads();
#pragma unroll
    for (int i = 0; i < 4; i++) {
        const int hh = ty + i * 16;
        ushort4 o;
        o.x = f2bf(t[tx * 4 + 0][hh]);
        o.y = f2bf(t[tx * 4 + 1][hh]);
        o.z = f2bf(t[tx * 4 + 2][hh]);
        o.w = f2bf(t[tx * 4 + 3][hh]);
        *(ushort4*)&xT[((size_t)(b * H_ + h0 + hh)) * C_ + c0 + tx * 4] = o;
    }
}

// ---- m97-style bf16 MFMA GEMM: C[m,n] = sum_k A[m,k]*W[n,k] + bias[n] ----
template<bool REMAP, bool FINAL>
__global__ __launch_bounds__(256)
void gemm_mfma(const unsigned short* __restrict__ A, const unsigned short* __restrict__ W,
               const float* __restrict__ bias, void* __restrict__ Cout,
               int M, int N, int K,
               const float* __restrict__ x, const float* __restrict__ scale)
{
    __shared__ unsigned short At[128 * 32];
    __shared__ unsigned short Wt[128 * 32];
    const int tid  = threadIdx.x;
    const int wave = tid >> 6;
    const int lane = tid & 63;
    const int quad = lane >> 4;
    const int l15  = lane & 15;
    const int m0 = blockIdx.y * 128;
    const int n0 = blockIdx.x * 128;
    const int rw = (wave >> 1) * 64;
    const int cw = (wave & 1) * 64;
    const int zb = FINAL ? blockIdx.z : 0;
    const unsigned short* Wb = FINAL ? W + (size_t)zb * N * K : W;

    const int srow = lane >> 2;
    const int scol = (lane & 3) * 8;

    f32x4 acc[4][4] = {};

    for (int k0 = 0; k0 < K; k0 += 32) {
        __syncthreads();
#pragma unroll
        for (int c = 0; c < 2; c++) {
            const int chunk = wave + c * 4;
            const unsigned short* ga = A  + (size_t)(m0 + chunk * 16 + srow) * K + k0 + scol;
            gl2lds16(ga, &At[chunk * 512]);
            const unsigned short* gw = Wb + (size_t)(n0 + chunk * 16 + srow) * K + k0 + scol;
            gl2lds16(gw, &Wt[chunk * 512]);
        }
        __syncthreads();
        bf16x8 af[4], wf[4];
#pragma unroll
        for (int i = 0; i < 4; i++)
            af[i] = *(const bf16x8*)&At[(rw + i * 16 + l15) * 32 + quad * 8];
#pragma unroll
        for (int j = 0; j < 4; j++)
            wf[j] = *(const bf16x8*)&Wt[(cw + j * 16 + l15) * 32 + quad * 8];
#pragma unroll
        for (int i = 0; i < 4; i++)
#pragma unroll
            for (int j = 0; j < 4; j++)
                acc[i][j] = __builtin_amdgcn_mfma_f32_16x16x32_bf16(af[i], wf[j], acc[i][j], 0, 0, 0);
    }

    if constexpr (!FINAL) {
        float bias4[4];
#pragma unroll
        for (int j = 0; j < 4; j++) bias4[j] = bias[n0 + cw + j * 16 + l15];
#pragma unroll
        for (int i = 0; i < 4; i++) {
#pragma unroll
            for (int r = 0; r < 4; r++) {
                const int mm = m0 + rw + i * 16 + quad * 4 + r;
                if (mm < M) {
                    const int orow = REMAP ? ((mm >> 10) * S1_ + (mm & 1023)) : mm;
                    unsigned short* cp = (unsigned short*)Cout + (size_t)orow * N + n0 + cw + l15;
#pragma unroll
                    for (int j = 0; j < 4; j++)
                        cp[j * 16] = f2bf(acc[i][j][r] + bias4[j]);
                }
            }
        }
    } else {
#pragma unroll
        for (int i = 0; i < 4; i++) {
#pragma unroll
            for (int r = 0; r < 4; r++) {
                const int mm = m0 + rw + i * 16 + quad * 4 + r;
                const float cb = bias[mm];
                const float sc = scale[zb * C_ + mm];
                const size_t base = ((size_t)(zb * C_ + mm)) * H_ + n0 + cw + l15;
#pragma unroll
                for (int j = 0; j < 4; j++)
                    ((float*)Cout)[base + j * 16] = (x[base + j * 16] + acc[i][j][r] + cb) * sc;
            }
        }
    }
}

// WqW16[e,c] = bf16(sum_k ipW[e,k]*q_W[k,c]);  qb2[e] = sum_k ipW[e,k]*q_b[k] + ipb[e]
__global__ __launch_bounds__(256)
void fuse_qw_kernel(const float* __restrict__ ipW, const float* __restrict__ ipb,
                    const float* __restrict__ q_W, const float* __restrict__ q_b,
                    unsigned short* __restrict__ WqW16, float* __restrict__ qb2)
{
    const int e = blockIdx.x;
    const int c = threadIdx.x;
    const float* wrow = ipW + (size_t)e * E_;
    float acc = 0.f;
    for (int k = 0; k < E_; k++) acc += wrow[k] * q_W[(size_t)k * C_ + c];
    WqW16[(size_t)e * C_ + c] = f2bf(acc);
    __shared__ float red[256];
    float bacc = 0.f;
    for (int k = c; k < E_; k += 256) bacc += wrow[k] * q_b[k];
    red[c] = bacc;
    __syncthreads();
    for (int s = 128; s > 0; s >>= 1) {
        if (c < s) red[c] += red[c + s];
        __syncthreads();
    }
    if (c == 0) qb2[e] = red[0] + ipb[e];
}

// static token + FiLM MLP; writes static row (bf16) into cond16; scale = 1 + tanh(film)
__global__ __launch_bounds__(256)
void static_film_kernel(const float* __restrict__ statIn,
                        const float* __restrict__ stat_W, const float* __restrict__ stat_b,
                        const float* __restrict__ fW1, const float* __restrict__ fb1,
                        const float* __restrict__ fW2, const float* __restrict__ fb2,
                        unsigned short* __restrict__ cond16, float* __restrict__ scaleOut)
{
    __shared__ float s_sh[DS_];
    __shared__ float st_sh[E_];
    __shared__ float h1_sh[E_];
    const int b = blockIdx.x, t = threadIdx.x;
    if (t < DS_) s_sh[t] = statIn[b * DS_ + t];
    __syncthreads();
    for (int e = t; e < E_; e += 256) {
        float acc = stat_b[e];
#pragma unroll 4
        for (int j = 0; j < DS_; j++) acc += s_sh[j] * stat_W[e * DS_ + j];
        st_sh[e] = acc;
        cond16[((size_t)(b * S1_ + S_)) * E_ + e] = f2bf(acc);
    }
    __syncthreads();
    for (int e = t; e < E_; e += 256) {
        float acc = fb1[e];
#pragma unroll 4
        for (int j = 0; j < E_; j++) acc += st_sh[j] * fW1[(size_t)e * E_ + j];
        h1_sh[e] = (acc >= 0.f) ? acc : 0.1f * acc;
    }
    __syncthreads();
    for (int c = t; c < C_; c += 256) {
        float acc = fb2[c];
#pragma unroll 4
        for (int j = 0; j < E_; j++) acc += h1_sh[j] * fW2[(size_t)c * E_ + j];
        scaleOut[b * C_ + c] = 1.f + tanhf(acc);
    }
}

// ---- MFMA flash attention, Q-tile = 256 (4 waves x 64 q), 32-key tiles ----
// kv layout: [b*S1 + s][1024]: cols 0..511 = K features, 512..1023 = V features.
#define KS 72
#define VS 76
#define PS 40

__global__ __launch_bounds__(256)
void attn_mfma_kernel(const unsigned short* __restrict__ q,
                      const unsigned short* __restrict__ kv,
                      const float* __restrict__ bt,
                      unsigned short* __restrict__ ctx)
{
    const int blk  = blockIdx.x;          // 512 blocks
    const int qt   = 3 - (blk >> 7);      // longest-first dispatch
    const int pair = blk & 127;
    const int nh   = pair & 7;
    const int b    = pair >> 3;
    const int tid  = threadIdx.x;
    const int wave = tid >> 6;
    const int lane = tid & 63;
    const int quad = lane >> 4;
    const int l15  = lane & 15;
    const int q0w  = qt * 256 + wave * 64;

    __shared__ unsigned short Kt[32 * KS];
    __shared__ unsigned short Vt[32 * VS];
    __shared__ unsigned short Pt[4][16 * PS];
    __shared__ float btl[2048];           // rel = qi-kk in [-1024,1023] -> btl[rel+1024]

    for (int i = tid; i < 2048; i += 256) btl[i] = bt[1023 + i];

    // Q A-fragments: 4 qfrags x 2 d-chunks
    bf16x8 qa[4][2];
    const size_t qbase = ((size_t)(b * H_ + q0w)) * E_ + nh * HD_;
#pragma unroll
    for (int qf = 0; qf < 4; qf++)
#pragma unroll
        for (int ch = 0; ch < 2; ch++)
            qa[qf][ch] = *(const bf16x8*)(q + qbase + (size_t)(qf * 16 + l15) * E_ + ch * 32 + quad * 8);

    bf16x8 ones;
#pragma unroll
    for (int j = 0; j < 8; j++) ((short*)&ones)[j] = (short)0x3F80;

    f32x4 o[4][4] = {};
    f32x4 lf[4] = {};
    bf16x8 pa[4];

    const int srow = tid >> 3;
    const int scol = (tid & 7) * 8;
    const int ntiles = 8 * qt + 9;        // causal tiles + static tile

    for (int t = 0; t < ntiles; t++) {
        const int k0 = (t == ntiles - 1) ? 1024 : t * 32;
        __syncthreads();
        {
            const size_t g = ((size_t)(b * S1_) + k0 + srow) * 1024 + nh * HD_ + scol;
            *(bf16x8*)&Kt[srow * KS + scol] = *(const bf16x8*)(kv + g);
            *(ushort4*)&Vt[srow * VS + scol]     = *(const ushort4*)(kv + g + 512);
            *(ushort4*)&Vt[srow * VS + scol + 4] = *(const ushort4*)(kv + g + 516);
        }
        __syncthreads();

        // phase A: S = QK^T, mask+bias+exp, P->LDS->A-frag (per qfrag pair)
#pragma unroll
        for (int qp = 0; qp < 2; qp++) {
            f32x4 s[2][2] = {};
#pragma unroll
            for (int ch = 0; ch < 2; ch++) {
                const bf16x8 kb0 = *(const bf16x8*)&Kt[l15 * KS + ch * 32 + quad * 8];
                const bf16x8 kb1 = *(const bf16x8*)&Kt[(16 + l15) * KS + ch * 32 + quad * 8];
                s[0][0] = __builtin_amdgcn_mfma_f32_16x16x32_bf16(qa[2 * qp][ch],     kb0, s[0][0], 0, 0, 0);
                s[1][0] = __builtin_amdgcn_mfma_f32_16x16x32_bf16(qa[2 * qp + 1][ch], kb0, s[1][0], 0, 0, 0);
                s[0][1] = __builtin_amdgcn_mfma_f32_16x16x32_bf16(qa[2 * qp][ch],     kb1, s[0][1], 0, 0, 0);
                s[1][1] = __builtin_amdgcn_mfma_f32_16x16x32_bf16(qa[2 * qp + 1][ch], kb1, s[1][1], 0, 0, 0);
            }
#pragma unroll
            for (int qq = 0; qq < 2; qq++) {
                const int qf = 2 * qp + qq;
                unsigned short* pw = Pt[wave];
#pragma unroll
                for (int f = 0; f < 2; f++) {
                    const int kk = k0 + f * 16 + l15;
#pragma unroll
                    for (int r = 0; r < 4; r++) {
                        const int qi = q0w + qf * 16 + quad * 4 + r;
                        const bool vis = (kk <= qi) || (kk == 1024);
                        const float pp = vis ? __expf(s[qq][f][r] * 0.125f + btl[qi - kk + 1024]) : 0.f;
                        pw[(quad * 4 + r) * PS + f * 16 + l15] = f2bf(pp);
                    }
                }
                pa[qf] = *(const bf16x8*)&pw[l15 * PS + quad * 8];
            }
        }

        // phase B: l += P@1 ; O += P@V
#pragma unroll
        for (int qf = 0; qf < 4; qf++)
            lf[qf] = __builtin_amdgcn_mfma_f32_16x16x32_bf16(pa[qf], ones, lf[qf], 0, 0, 0);
#pragma unroll
        for (int dt = 0; dt < 4; dt++) {
            bf16x8 vb;
#pragma unroll
            for (int j = 0; j < 8; j++)
                ((short*)&vb)[j] = (short)Vt[(quad * 8 + j) * VS + dt * 16 + l15];
#pragma unroll
            for (int qf = 0; qf < 4; qf++)
                o[qf][dt] = __builtin_amdgcn_mfma_f32_16x16x32_bf16(pa[qf], vb, o[qf][dt], 0, 0, 0);
        }
    }

    // epilogue
#pragma unroll
    for (int qf = 0; qf < 4; qf++) {
        unsigned short* crow = ctx + ((size_t)(b * H_ + q0w + qf * 16 + quad * 4)) * E_ + nh * HD_ + l15;
#pragma unroll
        for (int r = 0; r < 4; r++) {
            const float inv = 1.f / lf[qf][r];
#pragma unroll
            for (int dt = 0; dt < 4; dt++)
                crow[(size_t)r * E_ + dt * 16] = f2bf(o[qf][dt][r] * inv);
        }
    }
}

extern "C" void kernel_launch(void* const* d_in, const int* in_sizes, int n_in,
                              void* d_out, int out_size, void* d_ws, size_t ws_size,
                              hipStream_t stream)
{
    (void)in_sizes; (void)n_in; (void)out_size; (void)ws_size;
    const float* x      = (const float*)d_in[0];
    const float* dyn    = (const float*)d_in[1];
    const float* statIn = (const float*)d_in[2];
    const float* dyn_W  = (const float*)d_in[3];
    const float* dyn_b  = (const float*)d_in[4];
    const float* stat_W = (const float*)d_in[5];
    const float* stat_b = (const float*)d_in[6];
    const float* fW1    = (const float*)d_in[7];
    const float* fb1    = (const float*)d_in[8];
    const float* fW2    = (const float*)d_in[9];
    const float* fb2    = (const float*)d_in[10];
    const float* q_W    = (const float*)d_in[11];
    const float* q_b    = (const float*)d_in[12];
    const float* ipW    = (const float*)d_in[13];
    const float* ipb    = (const float*)d_in[14];
    const float* out_W  = (const float*)d_in[15];
    const float* out_b  = (const float*)d_in[16];
    const float* ctx_W  = (const float*)d_in[17];
    const float* ctx_b  = (const float*)d_in[18];
    const float* bt     = (const float*)d_in[19];
    float* out = (float*)d_out;

    // ---- workspace layout, ~78.5 MB (<84.6 proven safe) ----
    const size_t CND_ROWS = 16512;                 // B*S1=16400 padded to 129*128
    char* w = (char*)d_ws; size_t off = 0;
    unsigned short* cond16  = (unsigned short*)(w + off); off += CND_ROWS * E_ * 2;           // 16.9 MB
    unsigned short* kv16    = (unsigned short*)(w + off); off += CND_ROWS * 1024 * 2;         // 33.8 MB
    unsigned short* dyn16   = (unsigned short*)(w + off); off += (size_t)B_ * S_ * DD_ * 2;   // 16.8 MB
    unsigned short* xT16    = (unsigned short*)(w + off); off += (size_t)B_ * H_ * C_ * 2;    // 8.4 MB
    unsigned short* dynW16  = (unsigned short*)(w + off); off += (size_t)E_ * DD_ * 2;
    unsigned short* ipWkv16 = (unsigned short*)(w + off); off += (size_t)2 * E_ * E_ * 2;
    unsigned short* outW16  = (unsigned short*)(w + off); off += (size_t)E_ * E_ * 2;
    unsigned short* ctxW16  = (unsigned short*)(w + off); off += (size_t)C_ * E_ * 2;
    unsigned short* WqW16   = (unsigned short*)(w + off); off += (size_t)E_ * C_ * 2;
    float* scaleB = (float*)(w + off); off += (size_t)B_ * C_ * 4;
    float* qb2    = (float*)(w + off); off += E_ * 4;
    // aliases over dead regions:
    unsigned short* q16    = dyn16;     // dyn dead after dyn-GEMM
    unsigned short* ctx16  = cond16;    // cond dead after KV GEMM
    unsigned short* ctxo16 = dyn16;     // q dead after attention

    // 1. bf16 conversions
    conv_bf16<<<(E_ * DD_ / 8 + 255) / 256, 256, 0, stream>>>(dyn_W, dynW16, E_ * DD_);
    conv_bf16<<<(2 * E_ * E_ / 8 + 255) / 256, 256, 0, stream>>>(ipW + (size_t)E_ * E_, ipWkv16, 2 * E_ * E_);
    conv_bf16<<<(E_ * E_ / 8 + 255) / 256, 256, 0, stream>>>(out_W, outW16, E_ * E_);
    conv_bf16<<<(C_ * E_ / 8 + 255) / 256, 256, 0, stream>>>(ctx_W, ctxW16, C_ * E_);
    conv_bf16<<<(B_ * S_ * DD_ / 8 + 255) / 256, 256, 0, stream>>>(dyn, dyn16, B_ * S_ * DD_);
    // 2. fused query weight + bias
    fuse_qw_kernel<<<E_, C_, 0, stream>>>(ipW, ipb, q_W, q_b, WqW16, qb2);
    // 3. x transpose -> xT16[b*H+h][c]
    xpose_kernel<<<dim3(H_ / 64, C_ / 64, B_), 256, 0, stream>>>(x, xT16);
    // 4. dyn tokens -> cond16 (row remap 1024->1025)
    gemm_mfma<true, false><<<dim3(E_ / 128, B_ * S_ / 128), 256, 0, stream>>>(
        dyn16, dynW16, dyn_b, cond16, B_ * S_, E_, DD_, nullptr, nullptr);
    // 5. static token row + FiLM scale
    static_film_kernel<<<B_, 256, 0, stream>>>(statIn, stat_W, stat_b, fW1, fb1, fW2, fb2,
                                               cond16, scaleB);
    // 6. q = xT @ WqW^T + qb2 -> q16
    gemm_mfma<false, false><<<dim3(E_ / 128, B_ * H_ / 128), 256, 0, stream>>>(
        xT16, WqW16, qb2, q16, B_ * H_, E_, C_, nullptr, nullptr);
    // 7. fused K|V projection -> kv16 [row][1024] (cols 0..511=K, 512..1023=V)
    gemm_mfma<false, false><<<dim3(1024 / 128, 129), 256, 0, stream>>>(
        cond16, ipWkv16, ipb + E_, kv16, B_ * S1_, 1024, E_, nullptr, nullptr);
    // 8. flash attention (Q-tile 256) -> ctx16 (over cond region)
    attn_mfma_kernel<<<512, 256, 0, stream>>>(q16, kv16, bt, ctx16);
    // 9. out projection -> ctxo16 (over dyn/q region)
    gemm_mfma<false, false><<<dim3(E_ / 128, B_ * H_ / 128), 256, 0, stream>>>(
        ctx16, outW16, out_b, ctxo16, B_ * H_, E_, E_, nullptr, nullptr);
    // 10. final: per-batch ctx_W @ ctxo^T, fused x + ctx_b + FiLM scale -> out (fp32)
    gemm_mfma<false, true><<<dim3(H_ / 128, C_ / 128, B_), 256, 0, stream>>>(
        ctxW16, ctxo16, ctx_b, out, C_, H_, E_, x, scaleB);
}